// Round 4
// baseline (1897.769 us; speedup 1.0000x reference)
//
#include <hip/hip_runtime.h>
#include <hip/hip_bf16.h>
#include <math.h>

#define NN 512
#define HH 32
#define PP 64
#define EE 512

// ---------------------------------------------------------------------------
// Kernel 0: prep derived params. One block per head h (32 blocks, 256 thr).
//   Wu[h][e]  = sum_d Wf[h*16+d] * Wv[h*16+d][e]          (32x512)
//   Wbp[h][p] = ln_p_g[p] * Wb[h][p]                      (32x64)
//   s1[h] = sum_p ln_p_g[p]*Wb[h][p]
//   s2[h] = sum_p ln_p_b[p]*Wb[h][p] + bb[h]
// ---------------------------------------------------------------------------
__global__ __launch_bounds__(256)
void prep_kernel(const float* __restrict__ Wv, const float* __restrict__ Wf,
                 const float* __restrict__ Wb, const float* __restrict__ pg,
                 const float* __restrict__ pb, const float* __restrict__ bbv,
                 float* __restrict__ Wu, float* __restrict__ Wbp,
                 float* __restrict__ s1, float* __restrict__ s2) {
    const int h = blockIdx.x;
    const int t = threadIdx.x;
    __shared__ float sh1[64], sh2[64];
#pragma unroll
    for (int r = 0; r < 2; ++r) {
        const int e = r * 256 + t;
        float acc = 0.f;
#pragma unroll
        for (int d = 0; d < 16; ++d)
            acc += Wf[h * 16 + d] * Wv[(size_t)(h * 16 + d) * EE + e];  // coalesced over e
        Wu[h * EE + e] = acc;
    }
    if (t < 64) {
        const float wb = Wb[h * PP + t];
        Wbp[h * PP + t] = pg[t] * wb;
        sh1[t] = pg[t] * wb;
        sh2[t] = pb[t] * wb;
    }
    __syncthreads();
    if (t == 0) {
        float a = 0.f, s = 0.f;
#pragma unroll
        for (int p = 0; p < 64; ++p) { a += sh1[p]; s += sh2[p]; }
        s1[h] = a;
        s2[h] = s + bbv[h];
    }
}

// ---------------------------------------------------------------------------
// Kernel 1: LayerNorm(query) -> xq   (2048 rows of 512)
// ---------------------------------------------------------------------------
__global__ __launch_bounds__(256)
void ln_query_kernel(const float* __restrict__ x, const float* __restrict__ g,
                     const float* __restrict__ b, float* __restrict__ xq) {
    const int row = blockIdx.x;
    const int t = threadIdx.x;
    const int wave = t >> 6, lane = t & 63;
    const float2 v = ((const float2*)(x + (size_t)row * EE))[t];
    float s = v.x + v.y;
    float ss = v.x * v.x + v.y * v.y;
#pragma unroll
    for (int o = 32; o > 0; o >>= 1) {
        s += __shfl_xor(s, o, 64);
        ss += __shfl_xor(ss, o, 64);
    }
    __shared__ float rs[4], rss[4];
    if (lane == 0) { rs[wave] = s; rss[wave] = ss; }
    __syncthreads();
    s = rs[0] + rs[1] + rs[2] + rs[3];
    ss = rss[0] + rss[1] + rss[2] + rss[3];
    const float mu = s * (1.f / 512.f);
    const float var = ss * (1.f / 512.f) - mu * mu;
    const float istd = rsqrtf(var + 1e-5f);
    const float2 gg = ((const float2*)g)[t];
    const float2 bb2 = ((const float2*)b)[t];
    float2 o;
    o.x = (v.x - mu) * istd * gg.x + bb2.x;
    o.y = (v.y - mu) * istd * gg.y + bb2.y;
    ((float2*)(xq + (size_t)row * EE))[t] = o;
}

// ---------------------------------------------------------------------------
// Kernel 2: projections GEMM.  C[2048 x 1056] = xq @ [Wq|Wk|Wu]^T
//   cols [0,512)    -> q scaled 0.25, stored [row][e]
//   cols [512,1024) -> k stored ktn[c][h][n][16]  (R4: d contiguous so the
//                      attn kernel reads each head's K-vector as 4 float4)
//   cols [1024,1056)-> u stored uT[c][h][n]
// 32x32 tiles, BK=32, 2x2 micro-tile, 256 thr. Grid 64x33 = 2112 blocks.
// ---------------------------------------------------------------------------
__global__ __launch_bounds__(256)
void proj_gemm_kernel(const float* __restrict__ xq, const float* __restrict__ Wq,
                      const float* __restrict__ Wk, const float* __restrict__ Wu,
                      float* __restrict__ qo, float* __restrict__ ktn,
                      float* __restrict__ uT) {
    __shared__ float As[32][33];   // [k][row]
    __shared__ float Bs[32][33];   // [k][col]
    const int t = threadIdx.x;
    const int row0 = blockIdx.x * 32;
    const int col0 = blockIdx.y * 32;
    const int tx = t & 15, ty = t >> 4;     // 2x2 micro-tile coords
    const int lr = t >> 3;                  // 0..31 tile row (A) / col (B)
    const int lk4 = (t & 7) * 4;            // k offset of this thread's float4

    const int gcb = col0 + lr;
    const float* wrow;
    if (gcb < 512) wrow = Wq + (size_t)gcb * EE;
    else if (gcb < 1024) wrow = Wk + (size_t)(gcb - 512) * EE;
    else wrow = Wu + (size_t)(gcb - 1024) * EE;
    const float* arow = xq + (size_t)(row0 + lr) * EE;

    float a00 = 0.f, a01 = 0.f, a10 = 0.f, a11 = 0.f;
#pragma unroll 1
    for (int k0 = 0; k0 < EE; k0 += 32) {
        const float4 av = *(const float4*)(arow + k0 + lk4);
        const float4 bv = *(const float4*)(wrow + k0 + lk4);
        __syncthreads();
        As[lk4 + 0][lr] = av.x; As[lk4 + 1][lr] = av.y;
        As[lk4 + 2][lr] = av.z; As[lk4 + 3][lr] = av.w;
        Bs[lk4 + 0][lr] = bv.x; Bs[lk4 + 1][lr] = bv.y;
        Bs[lk4 + 2][lr] = bv.z; Bs[lk4 + 3][lr] = bv.w;
        __syncthreads();
#pragma unroll
        for (int kk = 0; kk < 32; ++kk) {
            const float2 a = *(const float2*)&As[kk][ty * 2];
            const float2 b = *(const float2*)&Bs[kk][tx * 2];
            a00 += a.x * b.x; a01 += a.x * b.y;
            a10 += a.y * b.x; a11 += a.y * b.y;
        }
    }

    float accv[2][2] = {{a00, a01}, {a10, a11}};
#pragma unroll
    for (int r = 0; r < 2; ++r) {
        const int grow = row0 + ty * 2 + r;
        const int c = grow >> 9, n = grow & 511;
#pragma unroll
        for (int cc = 0; cc < 2; ++cc) {
            const int gc = col0 + tx * 2 + cc;
            const float v = accv[r][cc];
            if (gc < 512) {
                qo[(size_t)grow * EE + gc] = v * 0.25f;
            } else if (gc < 1024) {
                const int e = gc - 512;
                const int h = e >> 4, d = e & 15;
                ktn[(((size_t)c * HH + h) * NN + n) * 16 + d] = v;
            } else {
                const int h = gc - 1024;
                uT[((size_t)c * HH + h) * NN + n] = v;
            }
        }
    }
}

// ---------------------------------------------------------------------------
// Kernel 3: fused attention+force. One block per (c,i), 512 threads, 1 j each.
// R4 structure: exp(logits) for all 32 heads live in REGISTERS (e32[32],
// statically indexed via fully-unrolled loops — dynamic indexing would go to
// scratch). No 64 KB LDS buffer, no barriers in the hot phase. Denominators
// via per-head wave butterfly -> part[32][8] in LDS (1 KB) -> 32-thread
// finish. __launch_bounds__(512, 4) raises the VGPR cap to 128 (the backend's
// default for 512-thr blocks is 64, which would spill the e32 array — R2
// showed what spills cost: 438 MB scratch writes).
// kt layout is now [c][h][n][16]: per head 4 contiguous float4 loads.
// ---------------------------------------------------------------------------
__global__ __launch_bounds__(512, 4)
void attn_force_kernel(const float* __restrict__ pair, const float* __restrict__ delta,
                       const float* __restrict__ qws, const float* __restrict__ ktn,
                       const float* __restrict__ uT, const float* __restrict__ Wbp,
                       const float* __restrict__ s1, const float* __restrict__ s2,
                       float* __restrict__ out) {
    __shared__ float part[HH][8];    // per-head per-wave partial denominators
    __shared__ float invd[HH];
    __shared__ float red[8][3];

    const int t = threadIdx.x;       // = j
    const int wave = t >> 6, lane = t & 63;
    const int bid = blockIdx.x;      // c*512 + i
    const int c = bid >> 9;
    const int i = bid & 511;
    const int j = t;

    const float4* prow = (const float4*)(pair + (((size_t)c * NN + i) * NN + j) * PP);
    const float* qrow = qws + (size_t)bid * EE;               // block-uniform -> s_load
    const float* ktb = ktn + (size_t)c * HH * NN * 16;

    float e32[32];                   // exp(logit) per head — registers only
    float mu = 0.f, istd = 0.f;
    float s = 0.f, ss = 0.f;

#pragma unroll
    for (int g = 0; g < 4; ++g) {
        float l8[8] = {0.f, 0.f, 0.f, 0.f, 0.f, 0.f, 0.f, 0.f};
#pragma unroll
        for (int x = 0; x < 16; ++x) {
            const float4 pv = prow[x];
            if (g == 0) {
                s += pv.x + pv.y + pv.z + pv.w;
                ss += pv.x * pv.x + pv.y * pv.y + pv.z * pv.z + pv.w * pv.w;
            }
#pragma unroll
            for (int hh = 0; hh < 8; ++hh) {
                const float4 wv = *(const float4*)(Wbp + (g * 8 + hh) * PP + x * 4);
                l8[hh] += pv.x * wv.x + pv.y * wv.y + pv.z * wv.z + pv.w * wv.w;
            }
        }
        if (g == 0) {
            mu = s * (1.f / 64.f);
            const float var = ss * (1.f / 64.f) - mu * mu;
            istd = rsqrtf(var + 1e-5f);
        }
#pragma unroll
        for (int hh = 0; hh < 8; ++hh) {
            const int h = g * 8 + hh;
            const float4* kv = (const float4*)(ktb + ((size_t)h * NN + j) * 16);
            const float4 k0 = kv[0], k1 = kv[1], k2 = kv[2], k3 = kv[3];
            const float4 q0 = *(const float4*)(qrow + h * 16 + 0);
            const float4 q1 = *(const float4*)(qrow + h * 16 + 4);
            const float4 q2 = *(const float4*)(qrow + h * 16 + 8);
            const float4 q3 = *(const float4*)(qrow + h * 16 + 12);
            float qk = k0.x * q0.x + k0.y * q0.y + k0.z * q0.z + k0.w * q0.w;
            qk += k1.x * q1.x + k1.y * q1.y + k1.z * q1.z + k1.w * q1.w;
            qk += k2.x * q2.x + k2.y * q2.y + k2.z * q2.z + k2.w * q2.w;
            qk += k3.x * q3.x + k3.y * q3.y + k3.z * q3.z + k3.w * q3.w;
            e32[h] = __expf(qk + istd * (l8[hh] - mu * s1[h]) + s2[h]);
        }
    }

    // ---- softmax denominators: per-head wave butterfly -> LDS partials ----
#pragma unroll
    for (int h = 0; h < HH; ++h) {
        float v = e32[h];
#pragma unroll
        for (int o = 32; o > 0; o >>= 1) v += __shfl_xor(v, o, 64);
        if (lane == 0) part[h][wave] = v;
    }
    __syncthreads();
    if (t < HH) {
        float d = 0.f;
#pragma unroll
        for (int w8 = 0; w8 < 8; ++w8) d += part[t][w8];
        invd[t] = 1.f / d;
    }
    __syncthreads();

    // ---- per-j weight (e from registers, invd broadcast from LDS) ----
    float w = 0.f;
    const float* urow = uT + (size_t)c * HH * NN + j;
#pragma unroll
    for (int h = 0; h < HH; ++h)
        w += e32[h] * invd[h] * urow[(size_t)h * NN];

    // ---- force reduction ----
    const float* d3 = delta + (((size_t)c * NN + i) * NN + j) * 3;
    float fx = w * d3[0], fy = w * d3[1], fz = w * d3[2];
#pragma unroll
    for (int o = 32; o > 0; o >>= 1) {
        fx += __shfl_xor(fx, o, 64);
        fy += __shfl_xor(fy, o, 64);
        fz += __shfl_xor(fz, o, 64);
    }
    if (lane == 0) { red[wave][0] = fx; red[wave][1] = fy; red[wave][2] = fz; }
    __syncthreads();
    if (t == 0) {
        float ox = 0.f, oy = 0.f, oz = 0.f;
#pragma unroll
        for (int w8 = 0; w8 < 8; ++w8) { ox += red[w8][0]; oy += red[w8][1]; oz += red[w8][2]; }
        out[(size_t)bid * 3 + 0] = ox;
        out[(size_t)bid * 3 + 1] = oy;
        out[(size_t)bid * 3 + 2] = oz;
    }
}

// ---------------------------------------------------------------------------
extern "C" void kernel_launch(void* const* d_in, const int* in_sizes, int n_in,
                              void* d_out, int out_size, void* d_ws, size_t ws_size,
                              hipStream_t stream) {
    const float* query   = (const float*)d_in[0];
    const float* pair    = (const float*)d_in[1];
    const float* delta   = (const float*)d_in[2];
    const float* ln_q_g  = (const float*)d_in[3];
    const float* ln_q_b  = (const float*)d_in[4];
    const float* ln_p_g  = (const float*)d_in[5];
    const float* ln_p_b  = (const float*)d_in[6];
    const float* Wq      = (const float*)d_in[7];
    const float* Wk      = (const float*)d_in[8];
    const float* Wv      = (const float*)d_in[9];
    const float* Wb      = (const float*)d_in[10];
    const float* bbv     = (const float*)d_in[11];
    const float* Wf      = (const float*)d_in[12];
    float* out = (float*)d_out;

    float* ws = (float*)d_ws;
    float* xq  = ws;                        // 2048*512
    float* qws = xq + 2048 * 512;           // 2048*512
    float* ktn = qws + 2048 * 512;          // 4*32*512*16 = 2048*512
    float* uT  = ktn + 2048 * 512;          // 4*32*512
    float* Wu  = uT + 4 * 32 * 512;         // 32*512
    float* Wbp = Wu + 32 * 512;             // 32*64
    float* s1  = Wbp + 32 * 64;             // 32
    float* s2  = s1 + 32;                   // 32

    prep_kernel<<<32, 256, 0, stream>>>(Wv, Wf, Wb, ln_p_g, ln_p_b, bbv,
                                        Wu, Wbp, s1, s2);
    ln_query_kernel<<<2048, 256, 0, stream>>>(query, ln_q_g, ln_q_b, xq);
    proj_gemm_kernel<<<dim3(64, 33), 256, 0, stream>>>(xq, Wq, Wk, Wu,
                                                       qws, ktn, uT);
    attn_force_kernel<<<2048, 512, 0, stream>>>(pair, delta, qws, ktn, uT,
                                                Wbp, s1, s2, out);
}

// Round 6
// 603.109 us; speedup vs baseline: 3.1466x; 3.1466x over previous
//
#include <hip/hip_runtime.h>
#include <hip/hip_bf16.h>
#include <math.h>

#define NN 512
#define HH 32
#define PP 64
#define EE 512

// ---------------------------------------------------------------------------
// Kernel 0: prep derived params. One block per head h (32 blocks, 256 thr).
//   Wu[h][e]  = sum_d Wf[h*16+d] * Wv[h*16+d][e]          (32x512)
//   Wbp[h][p] = ln_p_g[p] * Wb[h][p]                      (32x64)
//   s1[h] = sum_p ln_p_g[p]*Wb[h][p]
//   s2[h] = sum_p ln_p_b[p]*Wb[h][p] + bb[h]
// ---------------------------------------------------------------------------
__global__ __launch_bounds__(256)
void prep_kernel(const float* __restrict__ Wv, const float* __restrict__ Wf,
                 const float* __restrict__ Wb, const float* __restrict__ pg,
                 const float* __restrict__ pb, const float* __restrict__ bbv,
                 float* __restrict__ Wu, float* __restrict__ Wbp,
                 float* __restrict__ s1, float* __restrict__ s2) {
    const int h = blockIdx.x;
    const int t = threadIdx.x;
    __shared__ float sh1[64], sh2[64];
#pragma unroll
    for (int r = 0; r < 2; ++r) {
        const int e = r * 256 + t;
        float acc = 0.f;
#pragma unroll
        for (int d = 0; d < 16; ++d)
            acc += Wf[h * 16 + d] * Wv[(size_t)(h * 16 + d) * EE + e];  // coalesced over e
        Wu[h * EE + e] = acc;
    }
    if (t < 64) {
        const float wb = Wb[h * PP + t];
        Wbp[h * PP + t] = pg[t] * wb;
        sh1[t] = pg[t] * wb;
        sh2[t] = pb[t] * wb;
    }
    __syncthreads();
    if (t == 0) {
        float a = 0.f, s = 0.f;
#pragma unroll
        for (int p = 0; p < 64; ++p) { a += sh1[p]; s += sh2[p]; }
        s1[h] = a;
        s2[h] = s + bbv[h];
    }
}

// ---------------------------------------------------------------------------
// Kernel 1: LayerNorm(query) -> xq   (2048 rows of 512)
// ---------------------------------------------------------------------------
__global__ __launch_bounds__(256)
void ln_query_kernel(const float* __restrict__ x, const float* __restrict__ g,
                     const float* __restrict__ b, float* __restrict__ xq) {
    const int row = blockIdx.x;
    const int t = threadIdx.x;
    const int wave = t >> 6, lane = t & 63;
    const float2 v = ((const float2*)(x + (size_t)row * EE))[t];
    float s = v.x + v.y;
    float ss = v.x * v.x + v.y * v.y;
#pragma unroll
    for (int o = 32; o > 0; o >>= 1) {
        s += __shfl_xor(s, o, 64);
        ss += __shfl_xor(ss, o, 64);
    }
    __shared__ float rs[4], rss[4];
    if (lane == 0) { rs[wave] = s; rss[wave] = ss; }
    __syncthreads();
    s = rs[0] + rs[1] + rs[2] + rs[3];
    ss = rss[0] + rss[1] + rss[2] + rss[3];
    const float mu = s * (1.f / 512.f);
    const float var = ss * (1.f / 512.f) - mu * mu;
    const float istd = rsqrtf(var + 1e-5f);
    const float2 gg = ((const float2*)g)[t];
    const float2 bb2 = ((const float2*)b)[t];
    float2 o;
    o.x = (v.x - mu) * istd * gg.x + bb2.x;
    o.y = (v.y - mu) * istd * gg.y + bb2.y;
    ((float2*)(xq + (size_t)row * EE))[t] = o;
}

// ---------------------------------------------------------------------------
// Kernel 2: projections GEMM.  C[2048 x 1056] = xq @ [Wq|Wk|Wu]^T
// R5 rewrite: 64x64 tile, 4x4 micro-tile, BK=16, 256 threads.
//   - 16 FMA per 2 ds_read_b128 (old: 4 FMA per 2 ds_read_b64 -> 4x ratio)
//   - LDS [16][68] padded: staging writes & b-reads are 2-way conflicts (free)
//   - register prefetch of next global tile issued before the FMA loop
//   cols [0,512)    -> q scaled 0.25, stored [row][e]
//   cols [512,1024) -> k stored ktn[c][h][n][16] (d contiguous for attn)
//   cols [1024,1056)-> u stored uT[c][h][n]
// Grid 32 x 17 (last col-tile half-guarded).
// ---------------------------------------------------------------------------
__global__ __launch_bounds__(256)
void proj_gemm_kernel(const float* __restrict__ xq, const float* __restrict__ Wq,
                      const float* __restrict__ Wk, const float* __restrict__ Wu,
                      float* __restrict__ qo, float* __restrict__ ktn,
                      float* __restrict__ uT) {
    __shared__ float As[16][68];   // [k][row], pad->2-way max
    __shared__ float Bs[16][68];   // [k][col]
    const int t = threadIdx.x;
    const int row0 = blockIdx.x * 64;
    const int col0 = blockIdx.y * 64;
    const int tx = t & 15, ty = t >> 4;     // 4x4 micro-tile coords
    const int srow = t >> 2;                // 0..63: staged A-row / B-col
    const int skq = (t & 3) * 4;            // staged k offset (float4)

    const float* arow = xq + (size_t)(row0 + srow) * EE;
    const int gcb = col0 + srow;
    const float* wrow;
    if (gcb < 512) wrow = Wq + (size_t)gcb * EE;
    else if (gcb < 1024) wrow = Wk + (size_t)(gcb - 512) * EE;
    else if (gcb < 1056) wrow = Wu + (size_t)(gcb - 1024) * EE;
    else wrow = Wq;                          // dummy row; results discarded

    float acc[4][4] = {{0.f}};
    float4 av = *(const float4*)(arow + skq);
    float4 bv = *(const float4*)(wrow + skq);
#pragma unroll 1
    for (int k0 = 0; k0 < EE; k0 += 16) {
        __syncthreads();
        As[skq + 0][srow] = av.x; As[skq + 1][srow] = av.y;
        As[skq + 2][srow] = av.z; As[skq + 3][srow] = av.w;
        Bs[skq + 0][srow] = bv.x; Bs[skq + 1][srow] = bv.y;
        Bs[skq + 2][srow] = bv.z; Bs[skq + 3][srow] = bv.w;
        __syncthreads();
        if (k0 + 16 < EE) {                  // prefetch next tile under FMAs
            av = *(const float4*)(arow + k0 + 16 + skq);
            bv = *(const float4*)(wrow + k0 + 16 + skq);
        }
#pragma unroll
        for (int kk = 0; kk < 16; ++kk) {
            const float4 a = *(const float4*)&As[kk][ty * 4];
            const float4 b = *(const float4*)&Bs[kk][tx * 4];
            acc[0][0] += a.x * b.x; acc[0][1] += a.x * b.y;
            acc[0][2] += a.x * b.z; acc[0][3] += a.x * b.w;
            acc[1][0] += a.y * b.x; acc[1][1] += a.y * b.y;
            acc[1][2] += a.y * b.z; acc[1][3] += a.y * b.w;
            acc[2][0] += a.z * b.x; acc[2][1] += a.z * b.y;
            acc[2][2] += a.z * b.z; acc[2][3] += a.z * b.w;
            acc[3][0] += a.w * b.x; acc[3][1] += a.w * b.y;
            acc[3][2] += a.w * b.z; acc[3][3] += a.w * b.w;
        }
    }

#pragma unroll
    for (int mi = 0; mi < 4; ++mi) {
        const int grow = row0 + ty * 4 + mi;
        const int c = grow >> 9, n = grow & 511;
#pragma unroll
        for (int ni = 0; ni < 4; ++ni) {
            const int gc = col0 + tx * 4 + ni;
            const float v = acc[mi][ni];
            if (gc < 512) {
                qo[(size_t)grow * EE + gc] = v * 0.25f;
            } else if (gc < 1024) {
                const int e = gc - 512;
                const int h = e >> 4, d = e & 15;
                ktn[(((size_t)c * HH + h) * NN + n) * 16 + d] = v;
            } else if (gc < 1056) {
                const int h = gc - 1024;
                uT[((size_t)c * HH + h) * NN + n] = v;
            }
        }
    }
}

// ---------------------------------------------------------------------------
// Kernel 3: fused attention+force — R0 structure (proven 238 us: 64 KB LDS,
// group-of-8 heads, 64 VGPR, plain __launch_bounds__). Occupancy is HW-capped
// at ~16 waves/CU for ~60-VGPR 512-thr blocks (R1/R3/R4 measured); do not
// touch the min-waves knob (R2: ,8 -> 32 VGPR; R4: ,4 -> still 64 + spill).
// Only change vs R0: K read via ktn[c][h][n][16] — 4 contiguous float4 per
// head instead of 8 strided float2 (halves qk load instructions; code path
// validated in R4).
// ---------------------------------------------------------------------------
__global__ __launch_bounds__(512)
void attn_force_kernel(const float* __restrict__ pair, const float* __restrict__ delta,
                       const float* __restrict__ qws, const float* __restrict__ ktn,
                       const float* __restrict__ uT, const float* __restrict__ Wbp,
                       const float* __restrict__ s1, const float* __restrict__ s2,
                       float* __restrict__ out) {
    __shared__ float attn[HH][NN];   // 64 KB: exp(logit)[h][j]
    __shared__ float invd[HH];
    __shared__ float red[8][3];

    const int t = threadIdx.x;       // = j
    const int wave = t >> 6, lane = t & 63;
    const int bid = blockIdx.x;      // c*512 + i
    const int c = bid >> 9;
    const int i = bid & 511;
    const int j = t;

    const float4* prow = (const float4*)(pair + (((size_t)c * NN + i) * NN + j) * PP);
    const float* qrow = qws + (size_t)bid * EE;               // block-uniform -> s_load
    const float* ktb = ktn + (size_t)c * HH * NN * 16;

    float mu = 0.f, istd = 0.f;
#pragma unroll 1
    for (int g = 0; g < 4; ++g) {
        float l8[8] = {0.f, 0.f, 0.f, 0.f, 0.f, 0.f, 0.f, 0.f};
        float s = 0.f, ss = 0.f;
#pragma unroll
        for (int x = 0; x < 16; ++x) {
            const float4 pv = prow[x];
            if (g == 0) {
                s += pv.x + pv.y + pv.z + pv.w;
                ss += pv.x * pv.x + pv.y * pv.y + pv.z * pv.z + pv.w * pv.w;
            }
#pragma unroll
            for (int hh = 0; hh < 8; ++hh) {
                const float4 wv = *(const float4*)(Wbp + (g * 8 + hh) * PP + x * 4);
                l8[hh] += pv.x * wv.x + pv.y * wv.y + pv.z * wv.z + pv.w * wv.w;
            }
        }
        if (g == 0) {
            mu = s * (1.f / 64.f);
            const float var = ss * (1.f / 64.f) - mu * mu;
            istd = rsqrtf(var + 1e-5f);
        }
#pragma unroll
        for (int hh = 0; hh < 8; ++hh) {
            const int h = g * 8 + hh;
            const float4* kv4 = (const float4*)(ktb + ((size_t)h * NN + j) * 16);
            const float4 k0v = kv4[0], k1v = kv4[1], k2v = kv4[2], k3v = kv4[3];
            const float4 q0 = *(const float4*)(qrow + h * 16 + 0);
            const float4 q1 = *(const float4*)(qrow + h * 16 + 4);
            const float4 q2 = *(const float4*)(qrow + h * 16 + 8);
            const float4 q3 = *(const float4*)(qrow + h * 16 + 12);
            float qk = k0v.x * q0.x + k0v.y * q0.y + k0v.z * q0.z + k0v.w * q0.w;
            qk += k1v.x * q1.x + k1v.y * q1.y + k1v.z * q1.z + k1v.w * q1.w;
            qk += k2v.x * q2.x + k2v.y * q2.y + k2v.z * q2.z + k2v.w * q2.w;
            qk += k3v.x * q3.x + k3v.y * q3.y + k3v.z * q3.z + k3v.w * q3.w;
            attn[h][j] = __expf(qk + istd * (l8[hh] - mu * s1[h]) + s2[h]);
        }
    }
    __syncthreads();

    // ---- softmax denominators: each wave owns heads [wave*4, wave*4+4) ----
#pragma unroll
    for (int q = 0; q < 4; ++q) {
        const int h = wave * 4 + q;
        float v = 0.f;
#pragma unroll
        for (int x = 0; x < 8; ++x) v += attn[h][x * 64 + lane];
#pragma unroll
        for (int o = 32; o > 0; o >>= 1) v += __shfl_xor(v, o, 64);
        if (lane == 0) invd[h] = 1.f / v;
    }
    __syncthreads();

    // ---- per-j weight, then force reduction ----
    float w = 0.f;
#pragma unroll
    for (int h = 0; h < HH; ++h)
        w += attn[h][j] * invd[h] * uT[((size_t)c * HH + h) * NN + j];

    const float* d3 = delta + (((size_t)c * NN + i) * NN + j) * 3;
    float fx = w * d3[0], fy = w * d3[1], fz = w * d3[2];
#pragma unroll
    for (int o = 32; o > 0; o >>= 1) {
        fx += __shfl_xor(fx, o, 64);
        fy += __shfl_xor(fy, o, 64);
        fz += __shfl_xor(fz, o, 64);
    }
    if (lane == 0) { red[wave][0] = fx; red[wave][1] = fy; red[wave][2] = fz; }
    __syncthreads();
    if (t == 0) {
        float ox = 0.f, oy = 0.f, oz = 0.f;
#pragma unroll
        for (int w8 = 0; w8 < 8; ++w8) { ox += red[w8][0]; oy += red[w8][1]; oz += red[w8][2]; }
        out[(size_t)bid * 3 + 0] = ox;
        out[(size_t)bid * 3 + 1] = oy;
        out[(size_t)bid * 3 + 2] = oz;
    }
}

// ---------------------------------------------------------------------------
extern "C" void kernel_launch(void* const* d_in, const int* in_sizes, int n_in,
                              void* d_out, int out_size, void* d_ws, size_t ws_size,
                              hipStream_t stream) {
    const float* query   = (const float*)d_in[0];
    const float* pair    = (const float*)d_in[1];
    const float* delta   = (const float*)d_in[2];
    const float* ln_q_g  = (const float*)d_in[3];
    const float* ln_q_b  = (const float*)d_in[4];
    const float* ln_p_g  = (const float*)d_in[5];
    const float* ln_p_b  = (const float*)d_in[6];
    const float* Wq      = (const float*)d_in[7];
    const float* Wk      = (const float*)d_in[8];
    const float* Wv      = (const float*)d_in[9];
    const float* Wb      = (const float*)d_in[10];
    const float* bbv     = (const float*)d_in[11];
    const float* Wf      = (const float*)d_in[12];
    float* out = (float*)d_out;

    float* ws = (float*)d_ws;
    float* xq  = ws;                        // 2048*512
    float* qws = xq + 2048 * 512;           // 2048*512
    float* ktn = qws + 2048 * 512;          // 4*32*512*16 = 2048*512
    float* uT  = ktn + 2048 * 512;          // 4*32*512
    float* Wu  = uT + 4 * 32 * 512;         // 32*512
    float* Wbp = Wu + 32 * 512;             // 32*64
    float* s1  = Wbp + 32 * 64;             // 32
    float* s2  = s1 + 32;                   // 32

    prep_kernel<<<32, 256, 0, stream>>>(Wv, Wf, Wb, ln_p_g, ln_p_b, bbv,
                                        Wu, Wbp, s1, s2);
    ln_query_kernel<<<2048, 256, 0, stream>>>(query, ln_q_g, ln_q_b, xq);
    proj_gemm_kernel<<<dim3(32, 17), 256, 0, stream>>>(xq, Wq, Wk, Wu,
                                                       qws, ktn, uT);
    attn_force_kernel<<<2048, 512, 0, stream>>>(pair, delta, qws, ktn, uT,
                                                Wbp, s1, s2, out);
}

// Round 7
// 565.457 us; speedup vs baseline: 3.3562x; 1.0666x over previous
//
#include <hip/hip_runtime.h>
#include <hip/hip_bf16.h>
#include <math.h>

#define NN 512
#define HH 32
#define PP 64
#define EE 512

// ---------------------------------------------------------------------------
// Kernel 0: prep derived params. One block per head h (32 blocks, 256 thr).
//   Wu[h][e]  = sum_d Wf[h*16+d] * Wv[h*16+d][e]          (32x512)
//   Wbp[h][p] = ln_p_g[p] * Wb[h][p]                      (32x64)
//   s1[h] = sum_p ln_p_g[p]*Wb[h][p]
//   s2[h] = sum_p ln_p_b[p]*Wb[h][p] + bb[h]
// ---------------------------------------------------------------------------
__global__ __launch_bounds__(256)
void prep_kernel(const float* __restrict__ Wv, const float* __restrict__ Wf,
                 const float* __restrict__ Wb, const float* __restrict__ pg,
                 const float* __restrict__ pb, const float* __restrict__ bbv,
                 float* __restrict__ Wu, float* __restrict__ Wbp,
                 float* __restrict__ s1, float* __restrict__ s2) {
    const int h = blockIdx.x;
    const int t = threadIdx.x;
    __shared__ float sh1[64], sh2[64];
#pragma unroll
    for (int r = 0; r < 2; ++r) {
        const int e = r * 256 + t;
        float acc = 0.f;
#pragma unroll
        for (int d = 0; d < 16; ++d)
            acc += Wf[h * 16 + d] * Wv[(size_t)(h * 16 + d) * EE + e];  // coalesced over e
        Wu[h * EE + e] = acc;
    }
    if (t < 64) {
        const float wb = Wb[h * PP + t];
        Wbp[h * PP + t] = pg[t] * wb;
        sh1[t] = pg[t] * wb;
        sh2[t] = pb[t] * wb;
    }
    __syncthreads();
    if (t == 0) {
        float a = 0.f, s = 0.f;
#pragma unroll
        for (int p = 0; p < 64; ++p) { a += sh1[p]; s += sh2[p]; }
        s1[h] = a;
        s2[h] = s + bbv[h];
    }
}

// ---------------------------------------------------------------------------
// Kernel 1: LayerNorm(query) -> xq   (2048 rows of 512)
// ---------------------------------------------------------------------------
__global__ __launch_bounds__(256)
void ln_query_kernel(const float* __restrict__ x, const float* __restrict__ g,
                     const float* __restrict__ b, float* __restrict__ xq) {
    const int row = blockIdx.x;
    const int t = threadIdx.x;
    const int wave = t >> 6, lane = t & 63;
    const float2 v = ((const float2*)(x + (size_t)row * EE))[t];
    float s = v.x + v.y;
    float ss = v.x * v.x + v.y * v.y;
#pragma unroll
    for (int o = 32; o > 0; o >>= 1) {
        s += __shfl_xor(s, o, 64);
        ss += __shfl_xor(ss, o, 64);
    }
    __shared__ float rs[4], rss[4];
    if (lane == 0) { rs[wave] = s; rss[wave] = ss; }
    __syncthreads();
    s = rs[0] + rs[1] + rs[2] + rs[3];
    ss = rss[0] + rss[1] + rss[2] + rss[3];
    const float mu = s * (1.f / 512.f);
    const float var = ss * (1.f / 512.f) - mu * mu;
    const float istd = rsqrtf(var + 1e-5f);
    const float2 gg = ((const float2*)g)[t];
    const float2 bb2 = ((const float2*)b)[t];
    float2 o;
    o.x = (v.x - mu) * istd * gg.x + bb2.x;
    o.y = (v.y - mu) * istd * gg.y + bb2.y;
    ((float2*)(xq + (size_t)row * EE))[t] = o;
}

// ---------------------------------------------------------------------------
// Kernel 2: projections GEMM.  C[2048 x 1056] = xq @ [Wq|Wk|Wu]^T
// R5 structure (kept: -24us vs old proj, measured R6): 64x64 tile, 4x4
// micro-tile, BK=16, 256 thr, padded [16][68] LDS, register prefetch.
// R7: kt store layout reverted to R0's [c][h][dp][n][2] — the attn kernel's
// proven-64-VGPR QK loop needs coalesced float2 loads (R6's [n][16] layout
// cost +4 VGPR -> occupancy cliff + 4x uncoalesced kt reads).
//   cols [0,512)    -> q scaled 0.25, stored [row][e]
//   cols [512,1024) -> k stored kt[c][h][dp][n][2]
//   cols [1024,1056)-> u stored uT[c][h][n]
// Grid 32 x 17 (last col-tile half-guarded).
// ---------------------------------------------------------------------------
__global__ __launch_bounds__(256)
void proj_gemm_kernel(const float* __restrict__ xq, const float* __restrict__ Wq,
                      const float* __restrict__ Wk, const float* __restrict__ Wu,
                      float* __restrict__ qo, float* __restrict__ kt,
                      float* __restrict__ uT) {
    __shared__ float As[16][68];   // [k][row], pad->2-way max
    __shared__ float Bs[16][68];   // [k][col]
    const int t = threadIdx.x;
    const int row0 = blockIdx.x * 64;
    const int col0 = blockIdx.y * 64;
    const int tx = t & 15, ty = t >> 4;     // 4x4 micro-tile coords
    const int srow = t >> 2;                // 0..63: staged A-row / B-col
    const int skq = (t & 3) * 4;            // staged k offset (float4)

    const float* arow = xq + (size_t)(row0 + srow) * EE;
    const int gcb = col0 + srow;
    const float* wrow;
    if (gcb < 512) wrow = Wq + (size_t)gcb * EE;
    else if (gcb < 1024) wrow = Wk + (size_t)(gcb - 512) * EE;
    else if (gcb < 1056) wrow = Wu + (size_t)(gcb - 1024) * EE;
    else wrow = Wq;                          // dummy row; results discarded

    float acc[4][4] = {{0.f}};
    float4 av = *(const float4*)(arow + skq);
    float4 bv = *(const float4*)(wrow + skq);
#pragma unroll 1
    for (int k0 = 0; k0 < EE; k0 += 16) {
        __syncthreads();
        As[skq + 0][srow] = av.x; As[skq + 1][srow] = av.y;
        As[skq + 2][srow] = av.z; As[skq + 3][srow] = av.w;
        Bs[skq + 0][srow] = bv.x; Bs[skq + 1][srow] = bv.y;
        Bs[skq + 2][srow] = bv.z; Bs[skq + 3][srow] = bv.w;
        __syncthreads();
        if (k0 + 16 < EE) {                  // prefetch next tile under FMAs
            av = *(const float4*)(arow + k0 + 16 + skq);
            bv = *(const float4*)(wrow + k0 + 16 + skq);
        }
#pragma unroll
        for (int kk = 0; kk < 16; ++kk) {
            const float4 a = *(const float4*)&As[kk][ty * 4];
            const float4 b = *(const float4*)&Bs[kk][tx * 4];
            acc[0][0] += a.x * b.x; acc[0][1] += a.x * b.y;
            acc[0][2] += a.x * b.z; acc[0][3] += a.x * b.w;
            acc[1][0] += a.y * b.x; acc[1][1] += a.y * b.y;
            acc[1][2] += a.y * b.z; acc[1][3] += a.y * b.w;
            acc[2][0] += a.z * b.x; acc[2][1] += a.z * b.y;
            acc[2][2] += a.z * b.z; acc[2][3] += a.z * b.w;
            acc[3][0] += a.w * b.x; acc[3][1] += a.w * b.y;
            acc[3][2] += a.w * b.z; acc[3][3] += a.w * b.w;
        }
    }

#pragma unroll
    for (int mi = 0; mi < 4; ++mi) {
        const int grow = row0 + ty * 4 + mi;
        const int c = grow >> 9, n = grow & 511;
#pragma unroll
        for (int ni = 0; ni < 4; ++ni) {
            const int gc = col0 + tx * 4 + ni;
            const float v = acc[mi][ni];
            if (gc < 512) {
                qo[(size_t)grow * EE + gc] = v * 0.25f;
            } else if (gc < 1024) {
                const int e = gc - 512;
                const int h = e >> 4, d = e & 15;
                kt[((((size_t)c * HH + h) * 8 + (d >> 1)) * NN + n) * 2 + (d & 1)] = v;
            } else if (gc < 1056) {
                const int h = gc - 1024;
                uT[((size_t)c * HH + h) * NN + n] = v;
            }
        }
    }
}

// ---------------------------------------------------------------------------
// Kernel 3: fused attention+force — byte-exact R0 structure (proven 238 us:
// 64 KB LDS, group-of-8 heads, 64 VGPR, coalesced float2 kt loads).
// DO NOT TOUCH: the 64-VGPR boundary is an occupancy cliff (R6: +4 VGPR ->
// occ 43%->23%, +37 us). min-waves knob forbidden (R2/R4: forced spills).
// R7's single addition: XCD-aware block swizzle — 2048 blocks = 8 XCDs x 256;
// contiguous 256-block chunks per XCD keep each chunk's kt+uT slice (4.25 MB)
// resident in that XCD's 4 MB L2 instead of all XCDs caching all 17 MB.
// Bijective (2048 % 8 == 0); affects only locality, not correctness.
// ---------------------------------------------------------------------------
__global__ __launch_bounds__(512)
void attn_force_kernel(const float* __restrict__ pair, const float* __restrict__ delta,
                       const float* __restrict__ qws, const float* __restrict__ kt,
                       const float* __restrict__ uT, const float* __restrict__ Wbp,
                       const float* __restrict__ s1, const float* __restrict__ s2,
                       float* __restrict__ out) {
    __shared__ float attn[HH][NN];   // 64 KB: exp(logit)[h][j]
    __shared__ float invd[HH];
    __shared__ float red[8][3];

    const int t = threadIdx.x;       // = j
    const int wave = t >> 6, lane = t & 63;
    const int bid0 = blockIdx.x;
    const int bid = ((bid0 & 7) << 8) | (bid0 >> 3);   // XCD swizzle: c*512 + i
    const int c = bid >> 9;
    const int i = bid & 511;
    const int j = t;

    const float4* prow = (const float4*)(pair + (((size_t)c * NN + i) * NN + j) * PP);
    const float* qrow = qws + (size_t)bid * EE;               // block-uniform -> s_load
    const float2* ktc = (const float2*)(kt + (size_t)c * HH * 8 * NN * 2);

    float mu = 0.f, istd = 0.f;
#pragma unroll 1
    for (int g = 0; g < 4; ++g) {
        float l8[8] = {0.f, 0.f, 0.f, 0.f, 0.f, 0.f, 0.f, 0.f};
        float s = 0.f, ss = 0.f;
#pragma unroll
        for (int x = 0; x < 16; ++x) {
            const float4 pv = prow[x];
            if (g == 0) {
                s += pv.x + pv.y + pv.z + pv.w;
                ss += pv.x * pv.x + pv.y * pv.y + pv.z * pv.z + pv.w * pv.w;
            }
#pragma unroll
            for (int hh = 0; hh < 8; ++hh) {
                const float4 w = *(const float4*)(Wbp + (g * 8 + hh) * PP + x * 4);
                l8[hh] += pv.x * w.x + pv.y * w.y + pv.z * w.z + pv.w * w.w;
            }
        }
        if (g == 0) {
            mu = s * (1.f / 64.f);
            const float var = ss * (1.f / 64.f) - mu * mu;
            istd = rsqrtf(var + 1e-5f);
        }
#pragma unroll
        for (int hh = 0; hh < 8; ++hh) {
            const int h = g * 8 + hh;
            float qk = 0.f;
#pragma unroll
            for (int dp = 0; dp < 8; ++dp) {
                const float2 kv = ktc[((size_t)h * 8 + dp) * NN + j];
                const float2 qv = *(const float2*)(qrow + h * 16 + dp * 2);
                qk += kv.x * qv.x + kv.y * qv.y;
            }
            attn[h][j] = __expf(qk + istd * (l8[hh] - mu * s1[h]) + s2[h]);
        }
    }
    __syncthreads();

    // ---- softmax denominators: each wave owns heads [wave*4, wave*4+4) ----
#pragma unroll
    for (int q = 0; q < 4; ++q) {
        const int h = wave * 4 + q;
        float v = 0.f;
#pragma unroll
        for (int x = 0; x < 8; ++x) v += attn[h][x * 64 + lane];
#pragma unroll
        for (int o = 32; o > 0; o >>= 1) v += __shfl_xor(v, o, 64);
        if (lane == 0) invd[h] = 1.f / v;
    }
    __syncthreads();

    // ---- per-j weight, then force reduction ----
    float w = 0.f;
#pragma unroll
    for (int h = 0; h < HH; ++h)
        w += attn[h][j] * invd[h] * uT[((size_t)c * HH + h) * NN + j];

    const float* d3 = delta + (((size_t)c * NN + i) * NN + j) * 3;
    float fx = w * d3[0], fy = w * d3[1], fz = w * d3[2];
#pragma unroll
    for (int o = 32; o > 0; o >>= 1) {
        fx += __shfl_xor(fx, o, 64);
        fy += __shfl_xor(fy, o, 64);
        fz += __shfl_xor(fz, o, 64);
    }
    if (lane == 0) { red[wave][0] = fx; red[wave][1] = fy; red[wave][2] = fz; }
    __syncthreads();
    if (t == 0) {
        float ox = 0.f, oy = 0.f, oz = 0.f;
#pragma unroll
        for (int w8 = 0; w8 < 8; ++w8) { ox += red[w8][0]; oy += red[w8][1]; oz += red[w8][2]; }
        out[(size_t)bid * 3 + 0] = ox;
        out[(size_t)bid * 3 + 1] = oy;
        out[(size_t)bid * 3 + 2] = oz;
    }
}

// ---------------------------------------------------------------------------
extern "C" void kernel_launch(void* const* d_in, const int* in_sizes, int n_in,
                              void* d_out, int out_size, void* d_ws, size_t ws_size,
                              hipStream_t stream) {
    const float* query   = (const float*)d_in[0];
    const float* pair    = (const float*)d_in[1];
    const float* delta   = (const float*)d_in[2];
    const float* ln_q_g  = (const float*)d_in[3];
    const float* ln_q_b  = (const float*)d_in[4];
    const float* ln_p_g  = (const float*)d_in[5];
    const float* ln_p_b  = (const float*)d_in[6];
    const float* Wq      = (const float*)d_in[7];
    const float* Wk      = (const float*)d_in[8];
    const float* Wv      = (const float*)d_in[9];
    const float* Wb      = (const float*)d_in[10];
    const float* bbv     = (const float*)d_in[11];
    const float* Wf      = (const float*)d_in[12];
    float* out = (float*)d_out;

    float* ws = (float*)d_ws;
    float* xq  = ws;                        // 2048*512
    float* qws = xq + 2048 * 512;           // 2048*512
    float* kt  = qws + 2048 * 512;          // 4*32*8*512*2 = 2048*512
    float* uT  = kt + 2048 * 512;           // 4*32*512
    float* Wu  = uT + 4 * 32 * 512;         // 32*512
    float* Wbp = Wu + 32 * 512;             // 32*64
    float* s1  = Wbp + 32 * 64;             // 32
    float* s2  = s1 + 32;                   // 32

    prep_kernel<<<32, 256, 0, stream>>>(Wv, Wf, Wb, ln_p_g, ln_p_b, bbv,
                                        Wu, Wbp, s1, s2);
    ln_query_kernel<<<2048, 256, 0, stream>>>(query, ln_q_g, ln_q_b, xq);
    proj_gemm_kernel<<<dim3(32, 17), 256, 0, stream>>>(xq, Wq, Wk, Wu,
                                                       qws, kt, uT);
    attn_force_kernel<<<2048, 512, 0, stream>>>(pair, delta, qws, kt, uT,
                                                Wbp, s1, s2, out);
}